// Round 1
// baseline (161.409 us; speedup 1.0000x reference)
//
#include <hip/hip_runtime.h>

static constexpr int DIN = 512;
static constexpr int DOUT = 256;

// ---------------- degree ----------------
__global__ void k_deg_init(float* __restrict__ deg, int n) {
  int i = blockIdx.x * blockDim.x + threadIdx.x;
  if (i < n) deg[i] = 1.0f;
}

__global__ void k_deg_accum(const int* __restrict__ ei_src, const float* __restrict__ ew,
                            float* __restrict__ deg, int E) {
  int e = blockIdx.x * blockDim.x + threadIdx.x;
  if (e < E) atomicAdd(&deg[ei_src[e]], ew[e]);
}

__global__ void k_rsqrt(const float* __restrict__ deg, float* __restrict__ s, int n) {
  int i = blockIdx.x * blockDim.x + threadIdx.x;
  if (i < n) s[i] = 1.0f / sqrtf(deg[i]);
}

// ---------------- GEMM: h1[i][j] = s[i] * dot(x[i,:], W[j,:]) ----------------
// x: [n, DIN] row-major; W: [DOUT, DIN] row-major. 64x64 tile, 4x4 per thread.
__global__ __launch_bounds__(256) void k_gemm(
    const float* __restrict__ x, const float* __restrict__ W,
    const float* __restrict__ s, float* __restrict__ h1) {
  __shared__ float xs[16][68];  // [k][m], pad 68 for bank spread, 16B-aligned rows
  __shared__ float ws[16][68];  // [k][n]
  const int tid = threadIdx.x;
  const int lr = tid >> 2;          // 0..63  (tile row for loading)
  const int lc = (tid & 3) * 4;     // 0,4,8,12 (k-offset for loading)
  const int tr = tid >> 4;          // 0..15
  const int tc = tid & 15;          // 0..15
  const int bm = blockIdx.y * 64;
  const int bn = blockIdx.x * 64;
  float acc[4][4] = {};
  const float* xg = x + (size_t)(bm + lr) * DIN + lc;
  const float* wg = W + (size_t)(bn + lr) * DIN + lc;
  for (int k0 = 0; k0 < DIN; k0 += 16) {
    float4 xv = *(const float4*)(xg + k0);
    float4 wv = *(const float4*)(wg + k0);
    __syncthreads();
    xs[lc + 0][lr] = xv.x; xs[lc + 1][lr] = xv.y;
    xs[lc + 2][lr] = xv.z; xs[lc + 3][lr] = xv.w;
    ws[lc + 0][lr] = wv.x; ws[lc + 1][lr] = wv.y;
    ws[lc + 2][lr] = wv.z; ws[lc + 3][lr] = wv.w;
    __syncthreads();
#pragma unroll
    for (int kk = 0; kk < 16; ++kk) {
      float4 av = *(const float4*)(&xs[kk][tr * 4]);
      float4 bv = *(const float4*)(&ws[kk][tc * 4]);
      float a[4] = {av.x, av.y, av.z, av.w};
      float b[4] = {bv.x, bv.y, bv.z, bv.w};
#pragma unroll
      for (int i = 0; i < 4; ++i)
#pragma unroll
        for (int j = 0; j < 4; ++j)
          acc[i][j] = fmaf(a[i], b[j], acc[i][j]);
    }
  }
#pragma unroll
  for (int i = 0; i < 4; ++i) {
    int row = bm + tr * 4 + i;
    float sr = s[row];
    float4 o;
    o.x = sr * acc[i][0]; o.y = sr * acc[i][1];
    o.z = sr * acc[i][2]; o.w = sr * acc[i][3];
    *(float4*)(h1 + (size_t)row * DOUT + bn + tc * 4) = o;
  }
}

// ---------------- CSR build (by dst) ----------------
__global__ void k_count(const int* __restrict__ ei_dst, int* __restrict__ counts, int E) {
  int e = blockIdx.x * blockDim.x + threadIdx.x;
  if (e < E) atomicAdd(&counts[ei_dst[e]], 1);
}

// single-block scan of n counts -> exclusive offsets [n+1]
__global__ __launch_bounds__(256) void k_scan(const int* __restrict__ counts,
                                              int* __restrict__ offs, int n) {
  __shared__ int sums[256];
  const int t = threadIdx.x;
  const int chunk = (n + 255) / 256;
  const int base = t * chunk;
  int sum = 0;
  for (int i = 0; i < chunk; ++i) {
    int idx = base + i;
    if (idx < n) sum += counts[idx];
  }
  sums[t] = sum;
  __syncthreads();
  for (int d = 1; d < 256; d <<= 1) {
    int v = (t >= d) ? sums[t - d] : 0;
    __syncthreads();
    sums[t] += v;
    __syncthreads();
  }
  int run = (t == 0) ? 0 : sums[t - 1];
  for (int i = 0; i < chunk; ++i) {
    int idx = base + i;
    if (idx < n) {
      offs[idx] = run;
      run += counts[idx];
    }
  }
  if (t == 255) offs[n] = run;
}

__global__ void k_fill(const int* __restrict__ ei, const float* __restrict__ ew,
                       int* __restrict__ cursor, int* __restrict__ csr_src,
                       float* __restrict__ csr_w, int E) {
  int e = blockIdx.x * blockDim.x + threadIdx.x;
  if (e < E) {
    int srcv = ei[e];
    int dstv = ei[E + e];
    int pos = atomicAdd(&cursor[dstv], 1);
    csr_src[pos] = srcv;
    csr_w[pos] = ew[e];
  }
}

// ---------------- gather: out[dst] = s[dst]*(h1[dst] + sum w*h1[src]) --------
__global__ __launch_bounds__(256) void k_gather(
    const float* __restrict__ h1, const float* __restrict__ s,
    const int* __restrict__ offs, const int* __restrict__ csr_src,
    const float* __restrict__ csr_w, float* __restrict__ out) {
  const int dst = blockIdx.x;
  const int t = threadIdx.x;
  const int o0 = offs[dst];
  const int o1 = offs[dst + 1];
  float acc = h1[(size_t)dst * DOUT + t];
  for (int e = o0; e < o1; ++e) {
    int src = csr_src[e];
    float w = csr_w[e];
    acc = fmaf(w, h1[(size_t)src * DOUT + t], acc);
  }
  out[(size_t)dst * DOUT + t] = s[dst] * acc;
}

// ---------------- atomic fallback (if ws too small for CSR) ----------------
__global__ __launch_bounds__(256) void k_out_init(
    const float* __restrict__ h1, const float* __restrict__ s, float* __restrict__ out) {
  const int dst = blockIdx.x;
  const int t = threadIdx.x;
  out[(size_t)dst * DOUT + t] = s[dst] * h1[(size_t)dst * DOUT + t];
}

__global__ __launch_bounds__(256) void k_scatter(
    const float* __restrict__ h1, const float* __restrict__ s,
    const int* __restrict__ ei, const float* __restrict__ ew,
    float* __restrict__ out, int E) {
  int gid = blockIdx.x * blockDim.x + threadIdx.x;
  int e = gid >> 6;
  int lane = gid & 63;
  if (e >= E) return;
  int srcv = ei[e];
  int dstv = ei[E + e];
  float c = ew[e] * s[dstv];
  float4 hv = *(const float4*)(h1 + (size_t)srcv * DOUT + lane * 4);
  float* op = out + (size_t)dstv * DOUT + lane * 4;
  atomicAdd(op + 0, c * hv.x);
  atomicAdd(op + 1, c * hv.y);
  atomicAdd(op + 2, c * hv.z);
  atomicAdd(op + 3, c * hv.w);
}

extern "C" void kernel_launch(void* const* d_in, const int* in_sizes, int n_in,
                              void* d_out, int out_size, void* d_ws, size_t ws_size,
                              hipStream_t stream) {
  const float* x = (const float*)d_in[0];
  const int* ei = (const int*)d_in[1];   // [2, E]: row0 = src, row1 = dst
  const float* ew = (const float*)d_in[2];
  const float* W = (const float*)d_in[3];
  float* out = (float*)d_out;

  const int n = in_sizes[0] / DIN;  // 8192
  const int E = in_sizes[2];        // 262144

  char* p = (char*)d_ws;
  float* h1 = (float*)p;     p += (size_t)n * DOUT * sizeof(float);
  float* s = (float*)p;      p += (size_t)n * sizeof(float);
  float* deg = (float*)p;    p += (size_t)n * sizeof(float);
  size_t need_base = (size_t)(p - (char*)d_ws);
  int* counts = (int*)p;     p += (size_t)n * sizeof(int);
  int* offs = (int*)p;       p += (size_t)(n + 1) * sizeof(int);
  int* cursor = (int*)p;     p += (size_t)n * sizeof(int);
  int* csr_src = (int*)p;    p += (size_t)E * sizeof(int);
  float* csr_w = (float*)p;  p += (size_t)E * sizeof(float);
  size_t need_csr = (size_t)(p - (char*)d_ws);
  const bool use_csr = (ws_size >= need_csr);
  (void)need_base;

  // 1) degree + scale
  k_deg_init<<<(n + 255) / 256, 256, 0, stream>>>(deg, n);
  k_deg_accum<<<(E + 255) / 256, 256, 0, stream>>>(ei, ew, deg, E);
  k_rsqrt<<<(n + 255) / 256, 256, 0, stream>>>(deg, s, n);

  // 2) h1 = s * (x @ W^T)
  dim3 ggrid(DOUT / 64, n / 64);
  k_gemm<<<ggrid, 256, 0, stream>>>(x, W, s, h1);

  if (use_csr) {
    // 3) CSR by dst
    hipMemsetAsync(counts, 0, (size_t)n * sizeof(int), stream);
    k_count<<<(E + 255) / 256, 256, 0, stream>>>(ei + E, counts, E);
    k_scan<<<1, 256, 0, stream>>>(counts, offs, n);
    hipMemcpyAsync(cursor, offs, (size_t)n * sizeof(int), hipMemcpyDeviceToDevice, stream);
    k_fill<<<(E + 255) / 256, 256, 0, stream>>>(ei, ew, cursor, csr_src, csr_w, E);
    // 4) gather
    k_gather<<<n, 256, 0, stream>>>(h1, s, offs, csr_src, csr_w, out);
  } else {
    k_out_init<<<n, 256, 0, stream>>>(h1, s, out);
    const long long total = (long long)E * 64;
    k_scatter<<<(int)((total + 255) / 256), 256, 0, stream>>>(h1, s, ei, ew, out, E);
  }
}

// Round 2
// 123.765 us; speedup vs baseline: 1.3042x; 1.3042x over previous
//
#include <hip/hip_runtime.h>

static constexpr int DIN = 512;
static constexpr int DOUT = 256;

typedef __attribute__((ext_vector_type(8))) short short8;
typedef __attribute__((ext_vector_type(4))) float f32x4;

__device__ inline unsigned short f2bf(float f) {
  unsigned int b = __float_as_uint(f);
  unsigned int r = (b + 0x7fffu + ((b >> 16) & 1u)) >> 16;
  return (unsigned short)r;
}
__device__ inline float bf_lo(unsigned int packed) { return __uint_as_float(packed << 16); }
__device__ inline float bf_hi(unsigned int packed) { return __uint_as_float(packed & 0xffff0000u); }

// ---------------- init: deg=1, counts=0 ----------------
__global__ void k_init(float* __restrict__ deg, int* __restrict__ counts, int n) {
  int i = blockIdx.x * blockDim.x + threadIdx.x;
  if (i < n) { deg[i] = 1.0f; counts[i] = 0; }
}

__global__ void k_deg_accum(const int* __restrict__ ei_src, const float* __restrict__ ew,
                            float* __restrict__ deg, int E) {
  int e = blockIdx.x * blockDim.x + threadIdx.x;
  if (e < E) atomicAdd(&deg[ei_src[e]], ew[e]);
}

__global__ void k_rsqrt(const float* __restrict__ deg, float* __restrict__ s, int n) {
  int i = blockIdx.x * blockDim.x + threadIdx.x;
  if (i < n) s[i] = 1.0f / sqrtf(deg[i]);
}

// ---------------- convert W (f32 -> bf16) ----------------
__global__ void k_cvt_w(const float* __restrict__ W, unsigned short* __restrict__ wb, int total4) {
  int i = blockIdx.x * blockDim.x + threadIdx.x;
  if (i < total4) {
    float4 v = *(const float4*)(W + (size_t)i * 4);
    ushort4 o;
    o.x = f2bf(v.x); o.y = f2bf(v.y); o.z = f2bf(v.z); o.w = f2bf(v.w);
    *(ushort4*)(wb + (size_t)i * 4) = o;
  }
}

// ---------------- GEMM: h1b[r][c] = bf16( s[r] * dot(x[r,:], W[c,:]) ) ------
// block = 256 threads = 4 waves; block handles 16 rows x 256 cols.
// wave w: cols [w*64, w*64+64) as 4 MFMA 16x16 tiles, K-loop over 512.
__global__ __launch_bounds__(256) void k_gemm_mfma(
    const float* __restrict__ x, const unsigned short* __restrict__ wb,
    const float* __restrict__ s, unsigned short* __restrict__ h1b) {
  const int lane = threadIdx.x & 63;
  const int wv = threadIdx.x >> 6;
  const int bm = blockIdx.x * 16;
  const int colb = wv * 64;
  const int r = lane & 15;   // A row / B col / C col within tile
  const int kg = lane >> 4;  // k-group (8 contiguous k elements)
  f32x4 acc[4] = {};
  const float* arow = x + (size_t)(bm + r) * DIN + kg * 8;
  for (int k0 = 0; k0 < DIN; k0 += 32) {
    float4 a0 = *(const float4*)(arow + k0);
    float4 a1 = *(const float4*)(arow + k0 + 4);
    short8 av;
    av[0] = (short)f2bf(a0.x); av[1] = (short)f2bf(a0.y);
    av[2] = (short)f2bf(a0.z); av[3] = (short)f2bf(a0.w);
    av[4] = (short)f2bf(a1.x); av[5] = (short)f2bf(a1.y);
    av[6] = (short)f2bf(a1.z); av[7] = (short)f2bf(a1.w);
#pragma unroll
    for (int nt = 0; nt < 4; ++nt) {
      const unsigned short* brow = wb + (size_t)(colb + nt * 16 + r) * DIN + kg * 8 + k0;
      short8 bv = *(const short8*)brow;
      acc[nt] = __builtin_amdgcn_mfma_f32_16x16x32_bf16(av, bv, acc[nt], 0, 0, 0);
    }
  }
#pragma unroll
  for (int i = 0; i < 4; ++i) {
    int row = bm + kg * 4 + i;
    float sr = s[row];
#pragma unroll
    for (int nt = 0; nt < 4; ++nt) {
      h1b[(size_t)row * DOUT + colb + nt * 16 + r] = f2bf(sr * acc[nt][i]);
    }
  }
}

// ---------------- CSR build (by dst) ----------------
__global__ void k_count(const int* __restrict__ ei_dst, int* __restrict__ counts, int E) {
  int e = blockIdx.x * blockDim.x + threadIdx.x;
  if (e < E) atomicAdd(&counts[ei_dst[e]], 1);
}

__global__ __launch_bounds__(256) void k_scan(const int* __restrict__ counts,
                                              int* __restrict__ offs, int n) {
  __shared__ int sums[256];
  const int t = threadIdx.x;
  const int chunk = (n + 255) / 256;
  const int base = t * chunk;
  int sum = 0;
  for (int i = 0; i < chunk; ++i) {
    int idx = base + i;
    if (idx < n) sum += counts[idx];
  }
  sums[t] = sum;
  __syncthreads();
  for (int d = 1; d < 256; d <<= 1) {
    int v = (t >= d) ? sums[t - d] : 0;
    __syncthreads();
    sums[t] += v;
    __syncthreads();
  }
  int run = (t == 0) ? 0 : sums[t - 1];
  for (int i = 0; i < chunk; ++i) {
    int idx = base + i;
    if (idx < n) {
      offs[idx] = run;
      run += counts[idx];
    }
  }
  if (t == 255) offs[n] = run;
}

__global__ void k_fill(const int* __restrict__ ei, const float* __restrict__ ew,
                       int* __restrict__ cursor, int* __restrict__ csr_src,
                       float* __restrict__ csr_w, int E) {
  int e = blockIdx.x * blockDim.x + threadIdx.x;
  if (e < E) {
    int srcv = ei[e];
    int dstv = ei[E + e];
    int pos = atomicAdd(&cursor[dstv], 1);
    csr_src[pos] = srcv;
    csr_w[pos] = ew[e];
  }
}

// ---------------- gather: out[dst] = s[dst]*(h1[dst] + sum w*h1[src]) --------
// one wave per dst; lane owns 4 columns (lane*4 .. lane*4+3)
__global__ __launch_bounds__(256) void k_gather(
    const unsigned short* __restrict__ h1b, const float* __restrict__ s,
    const int* __restrict__ offs, const int* __restrict__ csr_src,
    const float* __restrict__ csr_w, float* __restrict__ out) {
  const int lane = threadIdx.x & 63;
  const int wv = threadIdx.x >> 6;
  const int dst = blockIdx.x * 4 + wv;
  const int o0 = offs[dst];
  const int o1 = offs[dst + 1];

  float a0 = 0.f, a1 = 0.f, a2 = 0.f, a3 = 0.f;

  for (int base = o0; base < o1; base += 64) {
    const int cnt = min(64, o1 - base);
    int sv = 0; float wl = 0.f;
    if (lane < cnt) {
      sv = csr_src[base + lane];
      wl = csr_w[base + lane];
    }
    int j = 0;
    for (; j + 8 <= cnt; j += 8) {
      uint2 rbuf[8];
#pragma unroll
      for (int u = 0; u < 8; ++u) {
        int src = __shfl(sv, j + u);
        rbuf[u] = *(const uint2*)(h1b + (size_t)src * DOUT + lane * 4);
      }
#pragma unroll
      for (int u = 0; u < 8; ++u) {
        float w = __shfl(wl, j + u);
        a0 = fmaf(w, bf_lo(rbuf[u].x), a0);
        a1 = fmaf(w, bf_hi(rbuf[u].x), a1);
        a2 = fmaf(w, bf_lo(rbuf[u].y), a2);
        a3 = fmaf(w, bf_hi(rbuf[u].y), a3);
      }
    }
    for (; j < cnt; ++j) {
      int src = __shfl(sv, j);
      float w = __shfl(wl, j);
      uint2 hv = *(const uint2*)(h1b + (size_t)src * DOUT + lane * 4);
      a0 = fmaf(w, bf_lo(hv.x), a0);
      a1 = fmaf(w, bf_hi(hv.x), a1);
      a2 = fmaf(w, bf_lo(hv.y), a2);
      a3 = fmaf(w, bf_hi(hv.y), a3);
    }
  }

  uint2 selfv = *(const uint2*)(h1b + (size_t)dst * DOUT + lane * 4);
  const float sd = s[dst];
  float4 o;
  o.x = sd * (bf_lo(selfv.x) + a0);
  o.y = sd * (bf_hi(selfv.x) + a1);
  o.z = sd * (bf_lo(selfv.y) + a2);
  o.w = sd * (bf_hi(selfv.y) + a3);
  *(float4*)(out + (size_t)dst * DOUT + lane * 4) = o;
}

extern "C" void kernel_launch(void* const* d_in, const int* in_sizes, int n_in,
                              void* d_out, int out_size, void* d_ws, size_t ws_size,
                              hipStream_t stream) {
  const float* x = (const float*)d_in[0];
  const int* ei = (const int*)d_in[1];  // [2, E]: row0 = src, row1 = dst
  const float* ew = (const float*)d_in[2];
  const float* W = (const float*)d_in[3];
  float* out = (float*)d_out;

  const int n = in_sizes[0] / DIN;  // 8192
  const int E = in_sizes[2];        // 262144

  // workspace layout (all 256B-aligned); total ~6.6 MB
  char* p = (char*)d_ws;
  auto alloc = [&](size_t bytes) {
    char* q = p;
    p += (bytes + 255) & ~(size_t)255;
    return q;
  };
  unsigned short* h1b = (unsigned short*)alloc((size_t)n * DOUT * 2);
  unsigned short* wb  = (unsigned short*)alloc((size_t)DOUT * DIN * 2);
  float* s    = (float*)alloc((size_t)n * 4);
  float* deg  = (float*)alloc((size_t)n * 4);
  int* counts = (int*)alloc((size_t)n * 4);
  int* offs   = (int*)alloc((size_t)(n + 1) * 4);
  int* cursor = (int*)alloc((size_t)n * 4);
  int* csr_src = (int*)alloc((size_t)E * 4);
  float* csr_w = (float*)alloc((size_t)E * 4);

  // 1) degree + scale
  k_init<<<(n + 255) / 256, 256, 0, stream>>>(deg, counts, n);
  k_deg_accum<<<(E + 255) / 256, 256, 0, stream>>>(ei, ew, deg, E);
  k_rsqrt<<<(n + 255) / 256, 256, 0, stream>>>(deg, s, n);

  // 2) W -> bf16; h1b = bf16(s * (x @ W^T))
  k_cvt_w<<<(DOUT * DIN / 4 + 255) / 256, 256, 0, stream>>>(W, wb, DOUT * DIN / 4);
  k_gemm_mfma<<<n / 16, 256, 0, stream>>>(x, wb, s, h1b);

  // 3) CSR by dst
  k_count<<<(E + 255) / 256, 256, 0, stream>>>(ei + E, counts, E);
  k_scan<<<1, 256, 0, stream>>>(counts, offs, n);
  hipMemcpyAsync(cursor, offs, (size_t)n * sizeof(int), hipMemcpyDeviceToDevice, stream);
  k_fill<<<(E + 255) / 256, 256, 0, stream>>>(ei, ew, cursor, csr_src, csr_w, E);

  // 4) gather
  k_gather<<<n / 4, 256, 0, stream>>>(h1b, s, offs, csr_src, csr_w, out);
}